// Round 6
// baseline (531.655 us; speedup 1.0000x reference)
//
#include <hip/hip_runtime.h>
#include <hip/hip_bf16.h>

#define NN 50000
#define EE 800000
#define DIMM 128

typedef __attribute__((ext_vector_type(8))) short bf16x8;
typedef __attribute__((ext_vector_type(8))) unsigned short us8;
typedef __attribute__((ext_vector_type(4))) float f32x4;

static __device__ __forceinline__ unsigned short f2bf(float f) {
    unsigned int u = __float_as_uint(f);
    unsigned int r = (u + 0x7fffu + ((u >> 16) & 1u)) >> 16;
    return (unsigned short)r;
}
static __device__ __forceinline__ float bf2f(unsigned short s) {
    return __uint_as_float(((unsigned int)s) << 16);
}

// ---------------- weight packing ----------------
__global__ __launch_bounds__(256) void pack_w(
    const float* __restrict__ Wq, const float* __restrict__ Wk,
    const float* __restrict__ Wv, const float* __restrict__ Ws,
    const float* __restrict__ bq, const float* __restrict__ bk,
    const float* __restrict__ bv, const float* __restrict__ bs,
    const float* __restrict__ Wf1, const float* __restrict__ Wf2,
    unsigned short* __restrict__ wqkvsT, unsigned short* __restrict__ wf1T,
    unsigned short* __restrict__ wf2T, float* __restrict__ biasq)
{
    int i = blockIdx.x * 256 + threadIdx.x;
    if (i < 65536) {                       // wqkvsT[n][k], n in [0,512)
        int n = i >> 7, k = i & 127;
        int sel = n >> 7, col = n & 127;
        const float* W = sel == 0 ? Wq : sel == 1 ? Wk : sel == 2 ? Wv : Ws;
        wqkvsT[i] = f2bf(W[k * 128 + col]);
    } else if (i < 131072) {               // wf1T[n][k]
        int j = i - 65536; int n = j >> 7, k = j & 127;
        wf1T[j] = f2bf(Wf1[k * 512 + n]);
    } else if (i < 196608) {               // wf2T[n][k]
        int j = i - 131072; int n = j >> 9, k = j & 511;
        wf2T[j] = f2bf(Wf2[k * 128 + n]);
    } else if (i < 197120) {
        int j = i - 196608; int sel = j >> 7;
        const float* bp = sel == 0 ? bq : sel == 1 ? bk : sel == 2 ? bv : bs;
        biasq[j] = bp[j & 127];
    }
}

// ---------------- bf16 MFMA GEMM, 128x128 tile (m93-shape) ----------------
// EPI 0: fp32 out + bias.  EPI 1: relu -> bf16 out + bias.  EPI 2: qkvs split.
template<bool A_BF16, int EPI>
__global__ __launch_bounds__(256) void gemm_k(
    const void* __restrict__ Ap, const unsigned short* __restrict__ Bt,
    const float* __restrict__ bias, void* __restrict__ Cp,
    float* __restrict__ qb, unsigned short* __restrict__ kvb, float* __restrict__ xrb,
    int M, int Nn, int K)
{
    __shared__ unsigned short As[128][72];
    __shared__ unsigned short Bs[128][72];
    int tid = threadIdx.x;
    int nb = Nn >> 7;                       // Nn / 128
    int bm = blockIdx.x / nb, bn = blockIdx.x % nb;
    int w = tid >> 6, lane = tid & 63;
    int wm = w >> 1, wn = w & 1;            // 2x2 waves, each 64 rows x 64 cols
    int lr = lane & 15, quad = lane >> 4;

    f32x4 acc[4][4];
    #pragma unroll
    for (int i = 0; i < 4; i++)
        #pragma unroll
        for (int j = 0; j < 4; j++) { f32x4 z = {0.f, 0.f, 0.f, 0.f}; acc[i][j] = z; }

    for (int kc = 0; kc < K; kc += 64) {
        #pragma unroll
        for (int it = 0; it < 4; ++it) {
            int row = it * 32 + (tid >> 3);
            int k8 = (tid & 7) * 8;
            int rg = bm * 128 + row;
            us8 st = {0, 0, 0, 0, 0, 0, 0, 0};
            if (rg < M) {
                if constexpr (A_BF16) {
                    st = *(const us8*)((const unsigned short*)Ap + (size_t)rg * K + kc + k8);
                } else {
                    const float* src = (const float*)Ap + (size_t)rg * K + kc + k8;
                    float4 f0 = *(const float4*)src;
                    float4 f1 = *(const float4*)(src + 4);
                    st[0] = f2bf(f0.x); st[1] = f2bf(f0.y); st[2] = f2bf(f0.z); st[3] = f2bf(f0.w);
                    st[4] = f2bf(f1.x); st[5] = f2bf(f1.y); st[6] = f2bf(f1.z); st[7] = f2bf(f1.w);
                }
            }
            *(us8*)&As[row][k8] = st;
            // B tile: same thread pattern, rows bn*128+row of Bt[Nn][K]
            *(us8*)&Bs[row][k8] = *(const us8*)(Bt + (size_t)(bn * 128 + row) * K + kc + k8);
        }
        __syncthreads();
        #pragma unroll
        for (int kk = 0; kk < 2; ++kk) {
            bf16x8 af[4], bfr[4];
            #pragma unroll
            for (int mi = 0; mi < 4; mi++)
                af[mi] = *(const bf16x8*)&As[wm * 64 + mi * 16 + lr][kk * 32 + quad * 8];
            #pragma unroll
            for (int ni = 0; ni < 4; ni++)
                bfr[ni] = *(const bf16x8*)&Bs[wn * 64 + ni * 16 + lr][kk * 32 + quad * 8];
            #pragma unroll
            for (int mi = 0; mi < 4; mi++)
                #pragma unroll
                for (int ni = 0; ni < 4; ni++)
                    acc[mi][ni] = __builtin_amdgcn_mfma_f32_16x16x32_bf16(af[mi], bfr[ni], acc[mi][ni], 0, 0, 0);
        }
        __syncthreads();
    }
    #pragma unroll
    for (int mi = 0; mi < 4; mi++) {
        #pragma unroll
        for (int ni = 0; ni < 4; ni++) {
            int cg = bn * 128 + wn * 64 + ni * 16 + lr;
            float bv = bias[cg];
            #pragma unroll
            for (int r = 0; r < 4; r++) {
                int rg = bm * 128 + wm * 64 + mi * 16 + quad * 4 + r;
                if (rg < M) {
                    float val = acc[mi][ni][r] + bv;
                    if constexpr (EPI == 0) {
                        ((float*)Cp)[(size_t)rg * Nn + cg] = val;
                    } else if constexpr (EPI == 1) {
                        val = fmaxf(val, 0.f);
                        ((unsigned short*)Cp)[(size_t)rg * Nn + cg] = f2bf(val);
                    } else {
                        int sel = cg >> 7, c = cg & 127;
                        if (sel == 0)      qb[(size_t)rg * 128 + c] = val;
                        else if (sel == 1) kvb[(size_t)rg * 256 + 2 * c] = f2bf(val);
                        else if (sel == 2) kvb[(size_t)rg * 256 + 2 * c + 1] = f2bf(val);
                        else               xrb[(size_t)rg * 128 + c] = val;
                    }
                }
            }
        }
    }
}

// ---------------- CSR build ----------------
__global__ __launch_bounds__(256) void hist_k(const int* __restrict__ dst, int* __restrict__ deg) {
    int e = blockIdx.x * 256 + threadIdx.x;
    if (e < EE) atomicAdd(&deg[dst[e]], 1);
}

__global__ __launch_bounds__(256) void scan_phaseA(const int* __restrict__ deg, int* __restrict__ rs,
                                                   int* __restrict__ bsum) {
    __shared__ int sm[256];
    int tid = threadIdx.x;
    int i = blockIdx.x * 256 + tid;
    int v = (i < NN) ? deg[i] : 0;
    sm[tid] = v;
    __syncthreads();
    #pragma unroll
    for (int off = 1; off < 256; off <<= 1) {
        int t = 0;
        if (tid >= off) t = sm[tid - off];
        __syncthreads();
        if (tid >= off) sm[tid] += t;
        __syncthreads();
    }
    if (i < NN) rs[i] = sm[tid] - v;
    if (tid == 255) bsum[blockIdx.x] = sm[255];
}

__global__ __launch_bounds__(256) void scan_phaseB(int* __restrict__ bsum, int nb) {
    __shared__ int sm[256];
    int tid = threadIdx.x;
    int v = (tid < nb) ? bsum[tid] : 0;
    sm[tid] = v;
    __syncthreads();
    #pragma unroll
    for (int off = 1; off < 256; off <<= 1) {
        int t = 0;
        if (tid >= off) t = sm[tid - off];
        __syncthreads();
        if (tid >= off) sm[tid] += t;
        __syncthreads();
    }
    if (tid < nb) bsum[tid] = sm[tid] - v;
}

__global__ __launch_bounds__(256) void scan_phaseC(int* __restrict__ rs, const int* __restrict__ bsum) {
    int i = blockIdx.x * 256 + threadIdx.x;
    if (i < NN) rs[i] += bsum[blockIdx.x];
    if (i == 0) rs[NN] = EE;
}

__global__ __launch_bounds__(256) void scatter_k(
    const int* __restrict__ src, const int* __restrict__ dst,
    const float* __restrict__ eattr, const int* __restrict__ rs,
    int* __restrict__ cur, int* __restrict__ srcs_sorted,
    unsigned short* __restrict__ eas)
{
    int e = blockIdx.x * 256 + threadIdx.x;
    if (e < EE) {
        int d = dst[e];
        int p = atomicAdd(&cur[d], 1);
        int pos = rs[d] + p;
        srcs_sorted[pos] = src[e];
        const float* ap = eattr + (size_t)e * 16;
        float4 a0 = *(const float4*)ap;
        float4 a1 = *(const float4*)(ap + 4);
        float4 a2 = *(const float4*)(ap + 8);
        float4 a3 = *(const float4*)(ap + 12);
        us8 lo, hi;
        lo[0] = f2bf(a0.x); lo[1] = f2bf(a0.y); lo[2] = f2bf(a0.z); lo[3] = f2bf(a0.w);
        lo[4] = f2bf(a1.x); lo[5] = f2bf(a1.y); lo[6] = f2bf(a1.z); lo[7] = f2bf(a1.w);
        hi[0] = f2bf(a2.x); hi[1] = f2bf(a2.y); hi[2] = f2bf(a2.z); hi[3] = f2bf(a2.w);
        hi[4] = f2bf(a3.x); hi[5] = f2bf(a3.y); hi[6] = f2bf(a3.z); hi[7] = f2bf(a3.w);
        *(us8*)(eas + (size_t)pos * 16)     = lo;
        *(us8*)(eas + (size_t)pos * 16 + 8) = hi;
    }
}

// ---------------- fused attention + beta gate + LN1 ----------------
// e-projection factored algebraically (R5); R6: 2-stage kv gather pipeline —
// each group's kv gather is issued one compute-group before consumption.
__global__ __launch_bounds__(256, 3) void attn_kernel(
    const float* __restrict__ q, const unsigned int* __restrict__ kvb,
    const float* __restrict__ xr, const float* __restrict__ x,
    const unsigned short* __restrict__ eas, const int* __restrict__ srcs,
    const int* __restrict__ rs,
    const float* __restrict__ We, const float* __restrict__ be,
    const float* __restrict__ Wbeta,
    const float* __restrict__ gamma1, const float* __restrict__ beta1,
    float* __restrict__ hout, unsigned int* __restrict__ hbf)
{
    int wave = threadIdx.x >> 6;
    int lane = threadIdx.x & 63;
    int n = blockIdx.x * 4 + wave;
    if (n >= NN) return;
    int c0 = lane * 2, c1 = c0 + 1;
    int jlane = lane & 15;           // position within 16-lane head group
    int hbase = lane & 48;           // first lane of my head group

    float be0 = be[c0], be1 = be[c1];

    float2 q2 = *(const float2*)(q + (size_t)n * 128 + c0);
    q2.x *= 0.17677669529663687f;    // 1/sqrt(32) folded into q
    q2.y *= 0.17677669529663687f;

    // qbe = (q/sqrt32)·be over my head's 32 channels
    float qbe = q2.x * be0 + q2.y * be1;
    qbe += __shfl_xor(qbe, 1); qbe += __shfl_xor(qbe, 2);
    qbe += __shfl_xor(qbe, 4); qbe += __shfl_xor(qbe, 8);
    // qwe_lane = sum_c q_c * We[jlane][c] over my head's channels (We reloaded in
    // epilogue instead of held in regs — frees 32 VGPRs for the kv double-buffer)
    float qwe = 0.f;
    #pragma unroll
    for (int j = 0; j < 16; j++) {
        float u = q2.x * We[j * 128 + c0] + q2.y * We[j * 128 + c1];
        u += __shfl_xor(u, 1); u += __shfl_xor(u, 2);
        u += __shfl_xor(u, 4); u += __shfl_xor(u, 8);
        if (jlane == j) qwe = u;
    }

    float l = 0.f, a0 = 0.f, a1 = 0.f, s = 0.f;
    int beg = rs[n], end = rs[n + 1];

    int sr0[8], sr1[8];
    unsigned short ea0[8], ea1[8];
    uint2 kv0[8], kv1[8];

#define LOADMETA(g, SR, EA) { \
    _Pragma("unroll") \
    for (int j = 0; j < 8; j++) { \
        int idx = min((g) + j, EE - 1); \
        SR[j] = srcs[idx]; \
        EA[j] = eas[(size_t)idx * 16 + jlane]; \
    } }
#define GATHER(SR, KV) { \
    _Pragma("unroll") \
    for (int j = 0; j < 8; j++) \
        KV[j] = *(const uint2*)(kvb + (size_t)SR[j] * 128 + (lane << 1)); }
#define COMPUTE(g, EA, KV) { \
    int cnt = end - (g); \
    _Pragma("unroll") \
    for (int j = 0; j < 8; j++) { \
        if (j < cnt) { \
            float ea = bf2f(EA[j]); \
            unsigned int kx = KV[j].x, ky = KV[j].y; \
            float k0 = __uint_as_float(kx << 16); \
            float v0 = __uint_as_float(kx & 0xffff0000u); \
            float k1 = __uint_as_float(ky << 16); \
            float v1 = __uint_as_float(ky & 0xffff0000u); \
            float part = fmaf(q2.x, k0, fmaf(q2.y, k1, qwe * ea)); \
            part += __shfl_xor(part, 1); \
            part += __shfl_xor(part, 2); \
            part += __shfl_xor(part, 4); \
            part += __shfl_xor(part, 8); \
            float wgt = __expf(part + qbe); \
            l += wgt; \
            a0 = fmaf(wgt, v0, a0); \
            a1 = fmaf(wgt, v1, a1); \
            s = fmaf(wgt, ea, s); \
        } } }

    LOADMETA(beg, sr0, ea0)
    GATHER(sr0, kv0)
    LOADMETA(beg + 8, sr1, ea1)
    for (int g = beg; g < end; g += 16) {
        GATHER(sr1, kv1)               // kv for group g+8 in flight during COMPUTE(g)
        COMPUTE(g, ea0, kv0)
        LOADMETA(g + 16, sr0, ea0)
        GATHER(sr0, kv0)               // kv for group g+16 in flight during COMPUTE(g+8)
        COMPUTE(g + 8, ea1, kv1)
        LOADMETA(g + 24, sr1, ea1)
    }
#undef LOADMETA
#undef GATHER
#undef COMPUTE

    // add e-contribution to output: (sum wgt*eattr)@We + l*be
    float eo0 = l * be0, eo1 = l * be1;
    #pragma unroll
    for (int j = 0; j < 16; j++) {
        float sj = __shfl(s, hbase + j);
        eo0 = fmaf(sj, We[j * 128 + c0], eo0);
        eo1 = fmaf(sj, We[j * 128 + c1], eo1);
    }
    a0 += eo0; a1 += eo1;

    float inv = l > 0.f ? 1.f / l : 0.f;
    float o0 = a0 * inv, o1 = a1 * inv;

    float wbo0 = Wbeta[c0],        wbo1 = Wbeta[c1];
    float wbx0 = Wbeta[128 + c0],  wbx1 = Wbeta[128 + c1];
    float wbd0 = Wbeta[256 + c0],  wbd1 = Wbeta[256 + c1];
    float2 xr2 = *(const float2*)(xr + (size_t)n * 128 + c0);
    float bl = o0 * wbo0 + o1 * wbo1 + xr2.x * wbx0 + xr2.y * wbx1
             + (o0 - xr2.x) * wbd0 + (o1 - xr2.y) * wbd1;
    #pragma unroll
    for (int off = 1; off < 64; off <<= 1) bl += __shfl_xor(bl, off);
    float beta = 1.f / (1.f + __expf(-bl));
    float xs0 = beta * xr2.x + (1.f - beta) * o0;
    float xs1 = beta * xr2.y + (1.f - beta) * o1;

    float2 xv = *(const float2*)(x + (size_t)n * 128 + c0);
    float t0 = xv.x + xs0, t1 = xv.y + xs1;
    float sm = t0 + t1;
    #pragma unroll
    for (int off = 1; off < 64; off <<= 1) sm += __shfl_xor(sm, off);
    float mu = sm * (1.f / 128.f);
    float d0 = t0 - mu, d1 = t1 - mu;
    float vv = d0 * d0 + d1 * d1;
    #pragma unroll
    for (int off = 1; off < 64; off <<= 1) vv += __shfl_xor(vv, off);
    float is = rsqrtf(vv * (1.f / 128.f) + 1e-5f);
    float h0 = d0 * is * gamma1[c0] + beta1[c0];
    float h1 = d1 * is * gamma1[c1] + beta1[c1];
    *(float2*)(hout + (size_t)n * 128 + c0) = make_float2(h0, h1);
    hbf[(size_t)n * 64 + lane] = (unsigned int)f2bf(h0) | ((unsigned int)f2bf(h1) << 16);
}

// ---------------- final LN over h + ff2 ----------------
__global__ __launch_bounds__(256) void ln2_k(
    const float* __restrict__ h, const float* __restrict__ ff2,
    const float* __restrict__ gamma2, const float* __restrict__ beta2,
    float* __restrict__ out)
{
    int wave = threadIdx.x >> 6;
    int lane = threadIdx.x & 63;
    int n = blockIdx.x * 4 + wave;
    if (n >= NN) return;
    int c0 = lane * 2;
    float2 hv = *(const float2*)(h + (size_t)n * 128 + c0);
    float2 fv = *(const float2*)(ff2 + (size_t)n * 128 + c0);
    float t0 = hv.x + fv.x, t1 = hv.y + fv.y;
    float sm = t0 + t1;
    #pragma unroll
    for (int off = 1; off < 64; off <<= 1) sm += __shfl_xor(sm, off);
    float mu = sm * (1.f / 128.f);
    float d0 = t0 - mu, d1 = t1 - mu;
    float vv = d0 * d0 + d1 * d1;
    #pragma unroll
    for (int off = 1; off < 64; off <<= 1) vv += __shfl_xor(vv, off);
    float is = rsqrtf(vv * (1.f / 128.f) + 1e-5f);
    float o0 = d0 * is * gamma2[c0] + beta2[c0];
    float o1 = d1 * is * gamma2[c0 + 1] + beta2[c0 + 1];
    *(float2*)(out + (size_t)n * 128 + c0) = make_float2(o0, o1);
}

extern "C" void kernel_launch(void* const* d_in, const int* in_sizes, int n_in,
                              void* d_out, int out_size, void* d_ws, size_t ws_size,
                              hipStream_t stream) {
    const float* x      = (const float*)d_in[0];
    const int*   eindex = (const int*)d_in[1];
    const float* eattr  = (const float*)d_in[2];
    const float* Wq = (const float*)d_in[3];  const float* bq = (const float*)d_in[4];
    const float* Wk = (const float*)d_in[5];  const float* bk = (const float*)d_in[6];
    const float* Wv = (const float*)d_in[7];  const float* bv = (const float*)d_in[8];
    const float* We = (const float*)d_in[9];  const float* be = (const float*)d_in[10];
    const float* Ws = (const float*)d_in[11]; const float* bs = (const float*)d_in[12];
    const float* Wbeta = (const float*)d_in[13];
    const float* g1 = (const float*)d_in[14]; const float* b1 = (const float*)d_in[15];
    const float* Wf1 = (const float*)d_in[16]; const float* bf1 = (const float*)d_in[17];
    const float* Wf2 = (const float*)d_in[18]; const float* bf2 = (const float*)d_in[19];
    const float* g2 = (const float*)d_in[20]; const float* b2 = (const float*)d_in[21];

    char* ws = (char*)d_ws;
    size_t off = 0;
    #define ALLOC(ptr, type, bytes) type* ptr = (type*)(ws + off); off = (off + (size_t)(bytes) + 255) & ~(size_t)255;
    ALLOC(wqkvsT, unsigned short, 512 * 128 * 2)
    ALLOC(wf1T,   unsigned short, 512 * 128 * 2)
    ALLOC(wf2T,   unsigned short, 128 * 512 * 2)
    ALLOC(biasq,  float,          512 * 4)
    ALLOC(qb,     float,          (size_t)NN * 128 * 4)     // 25.6 MB
    ALLOC(kvb,    unsigned short, (size_t)NN * 256 * 2)     // 25.6 MB (overlaid by ff1 w/ qb)
    ALLOC(xrb,    float,          (size_t)NN * 128 * 4)     // 25.6 MB (overlaid by ff2)
    ALLOC(h,      float,          (size_t)NN * 128 * 4)     // 25.6 MB
    ALLOC(hbf,    unsigned int,   (size_t)NN * 128 * 2)     // 12.8 MB
    ALLOC(deg,    int,            2 * NN * 4)               // deg[NN] + cursor[NN], one region
    ALLOC(row_start, int,         (NN + 1) * 4)
    ALLOC(bsum,   int,            1024)
    ALLOC(srcs_sorted, int,       (size_t)EE * 4)           // 3.2 MB
    ALLOC(eas,    unsigned short, (size_t)EE * 16 * 2)      // 25.6 MB
    #undef ALLOC
    int* cursor = deg + NN;
    unsigned short* ff1 = (unsigned short*)qb;   // qb+kvb contiguous
    float* ff2 = xrb;

    hipMemsetAsync(deg, 0, (size_t)2 * NN * 4, stream);

    pack_w<<<770, 256, 0, stream>>>(Wq, Wk, Wv, Ws, bq, bk, bv, bs, Wf1, Wf2,
                                    wqkvsT, wf1T, wf2T, biasq);

    // q|k|v|xr projections with split epilogue (128x128 tiles)
    gemm_k<false, 2><<<391 * 4, 256, 0, stream>>>(x, wqkvsT, biasq, nullptr,
                                                  qb, kvb, xrb, NN, 512, 128);

    // CSR by dst + permuted src/eattr
    hist_k<<<3125, 256, 0, stream>>>(eindex + EE, deg);
    scan_phaseA<<<196, 256, 0, stream>>>(deg, row_start, bsum);
    scan_phaseB<<<1, 256, 0, stream>>>(bsum, 196);
    scan_phaseC<<<196, 256, 0, stream>>>(row_start, bsum);
    scatter_k<<<3125, 256, 0, stream>>>(eindex, eindex + EE, eattr, row_start,
                                        cursor, srcs_sorted, eas);

    // fused attention + beta gate + residual + LN1
    attn_kernel<<<12500, 256, 0, stream>>>(qb, (const unsigned int*)kvb, xrb, x,
                                           eas, srcs_sorted, row_start,
                                           We, be, Wbeta, g1, b1, h, hbf);

    // FFN (ff1 overlays qb/kvb; ff2 overlays xrb — both dead after attn)
    gemm_k<true, 1><<<391 * 4, 256, 0, stream>>>(hbf, wf1T, bf1, ff1,
                                                 nullptr, nullptr, nullptr, NN, 512, 128);
    gemm_k<true, 0><<<391 * 1, 256, 0, stream>>>(ff1, wf2T, bf2, ff2,
                                                 nullptr, nullptr, nullptr, NN, 128, 512);

    // final LN
    ln2_k<<<12500, 256, 0, stream>>>(h, ff2, g2, b2, (float*)d_out);
}

// Round 7
// 523.856 us; speedup vs baseline: 1.0149x; 1.0149x over previous
//
#include <hip/hip_runtime.h>
#include <hip/hip_bf16.h>

#define NN 50000
#define EE 800000
#define DIMM 128

typedef __attribute__((ext_vector_type(8))) short bf16x8;
typedef __attribute__((ext_vector_type(8))) unsigned short us8;
typedef __attribute__((ext_vector_type(4))) float f32x4;

static __device__ __forceinline__ unsigned short f2bf(float f) {
    unsigned int u = __float_as_uint(f);
    unsigned int r = (u + 0x7fffu + ((u >> 16) & 1u)) >> 16;
    return (unsigned short)r;
}
static __device__ __forceinline__ float bf2f(unsigned short s) {
    return __uint_as_float(((unsigned int)s) << 16);
}

// sum across the 16-lane DPP row (head group) — full-rate VALU, no LDS
#define RED16(v) do { int _t; \
    _t = __builtin_amdgcn_update_dpp(0, __float_as_int(v), 0x128, 0xF, 0xF, true); v += __int_as_float(_t); \
    _t = __builtin_amdgcn_update_dpp(0, __float_as_int(v), 0x124, 0xF, 0xF, true); v += __int_as_float(_t); \
    _t = __builtin_amdgcn_update_dpp(0, __float_as_int(v), 0x122, 0xF, 0xF, true); v += __int_as_float(_t); \
    _t = __builtin_amdgcn_update_dpp(0, __float_as_int(v), 0x121, 0xF, 0xF, true); v += __int_as_float(_t); \
} while (0)

// ---------------- weight packing ----------------
__global__ __launch_bounds__(256) void pack_w(
    const float* __restrict__ Wq, const float* __restrict__ Wk,
    const float* __restrict__ Wv, const float* __restrict__ Ws,
    const float* __restrict__ bq, const float* __restrict__ bk,
    const float* __restrict__ bv, const float* __restrict__ bs,
    const float* __restrict__ Wf1, const float* __restrict__ Wf2,
    unsigned short* __restrict__ wqkvsT, unsigned short* __restrict__ wf1T,
    unsigned short* __restrict__ wf2T, float* __restrict__ biasq)
{
    int i = blockIdx.x * 256 + threadIdx.x;
    if (i < 65536) {                       // wqkvsT[n][k], n in [0,512)
        int n = i >> 7, k = i & 127;
        int sel = n >> 7, col = n & 127;
        const float* W = sel == 0 ? Wq : sel == 1 ? Wk : sel == 2 ? Wv : Ws;
        wqkvsT[i] = f2bf(W[k * 128 + col]);
    } else if (i < 131072) {               // wf1T[n][k]
        int j = i - 65536; int n = j >> 7, k = j & 127;
        wf1T[j] = f2bf(Wf1[k * 512 + n]);
    } else if (i < 196608) {               // wf2T[n][k]
        int j = i - 131072; int n = j >> 9, k = j & 511;
        wf2T[j] = f2bf(Wf2[k * 128 + n]);
    } else if (i < 197120) {
        int j = i - 196608; int sel = j >> 7;
        const float* bp = sel == 0 ? bq : sel == 1 ? bk : sel == 2 ? bv : bs;
        biasq[j] = bp[j & 127];
    }
}

// ---------------- bf16 MFMA GEMM, 128x128 tile ----------------
// EPI 0: fp32 out + bias.  EPI 1: relu -> bf16 out + bias.  EPI 2: qkvs split.
template<bool A_BF16, int EPI>
__global__ __launch_bounds__(256) void gemm_k(
    const void* __restrict__ Ap, const unsigned short* __restrict__ Bt,
    const float* __restrict__ bias, void* __restrict__ Cp,
    float* __restrict__ qb, unsigned short* __restrict__ kvb, float* __restrict__ xrb,
    int M, int Nn, int K)
{
    __shared__ unsigned short As[128][72];
    __shared__ unsigned short Bs[128][72];
    int tid = threadIdx.x;
    int nb = Nn >> 7;
    int bm = blockIdx.x / nb, bn = blockIdx.x % nb;
    int w = tid >> 6, lane = tid & 63;
    int wm = w >> 1, wn = w & 1;
    int lr = lane & 15, quad = lane >> 4;

    f32x4 acc[4][4];
    #pragma unroll
    for (int i = 0; i < 4; i++)
        #pragma unroll
        for (int j = 0; j < 4; j++) { f32x4 z = {0.f, 0.f, 0.f, 0.f}; acc[i][j] = z; }

    for (int kc = 0; kc < K; kc += 64) {
        #pragma unroll
        for (int it = 0; it < 4; ++it) {
            int row = it * 32 + (tid >> 3);
            int k8 = (tid & 7) * 8;
            int rg = bm * 128 + row;
            us8 st = {0, 0, 0, 0, 0, 0, 0, 0};
            if (rg < M) {
                if constexpr (A_BF16) {
                    st = *(const us8*)((const unsigned short*)Ap + (size_t)rg * K + kc + k8);
                } else {
                    const float* src = (const float*)Ap + (size_t)rg * K + kc + k8;
                    float4 f0 = *(const float4*)src;
                    float4 f1 = *(const float4*)(src + 4);
                    st[0] = f2bf(f0.x); st[1] = f2bf(f0.y); st[2] = f2bf(f0.z); st[3] = f2bf(f0.w);
                    st[4] = f2bf(f1.x); st[5] = f2bf(f1.y); st[6] = f2bf(f1.z); st[7] = f2bf(f1.w);
                }
            }
            *(us8*)&As[row][k8] = st;
            *(us8*)&Bs[row][k8] = *(const us8*)(Bt + (size_t)(bn * 128 + row) * K + kc + k8);
        }
        __syncthreads();
        #pragma unroll
        for (int kk = 0; kk < 2; ++kk) {
            bf16x8 af[4], bfr[4];
            #pragma unroll
            for (int mi = 0; mi < 4; mi++)
                af[mi] = *(const bf16x8*)&As[wm * 64 + mi * 16 + lr][kk * 32 + quad * 8];
            #pragma unroll
            for (int ni = 0; ni < 4; ni++)
                bfr[ni] = *(const bf16x8*)&Bs[wn * 64 + ni * 16 + lr][kk * 32 + quad * 8];
            #pragma unroll
            for (int mi = 0; mi < 4; mi++)
                #pragma unroll
                for (int ni = 0; ni < 4; ni++)
                    acc[mi][ni] = __builtin_amdgcn_mfma_f32_16x16x32_bf16(af[mi], bfr[ni], acc[mi][ni], 0, 0, 0);
        }
        __syncthreads();
    }
    #pragma unroll
    for (int mi = 0; mi < 4; mi++) {
        #pragma unroll
        for (int ni = 0; ni < 4; ni++) {
            int cg = bn * 128 + wn * 64 + ni * 16 + lr;
            float bv = bias[cg];
            #pragma unroll
            for (int r = 0; r < 4; r++) {
                int rg = bm * 128 + wm * 64 + mi * 16 + quad * 4 + r;
                if (rg < M) {
                    float val = acc[mi][ni][r] + bv;
                    if constexpr (EPI == 0) {
                        ((float*)Cp)[(size_t)rg * Nn + cg] = val;
                    } else if constexpr (EPI == 1) {
                        val = fmaxf(val, 0.f);
                        ((unsigned short*)Cp)[(size_t)rg * Nn + cg] = f2bf(val);
                    } else {
                        int sel = cg >> 7, c = cg & 127;
                        if (sel == 0)      qb[(size_t)rg * 128 + c] = val;
                        else if (sel == 1) kvb[(size_t)rg * 256 + 2 * c] = f2bf(val);
                        else if (sel == 2) kvb[(size_t)rg * 256 + 2 * c + 1] = f2bf(val);
                        else               xrb[(size_t)rg * 128 + c] = val;
                    }
                }
            }
        }
    }
}

// ---------------- qwe precompute: qweb[n][64] = (q_scaled @ We^T) per (head, j) ----------------
// lane = head*16 + j owns an independent 32-length dot product — no reductions.
__global__ __launch_bounds__(256) void qwe_k(
    const float* __restrict__ q, const float* __restrict__ We,
    float* __restrict__ qweb)
{
    int wave = threadIdx.x >> 6, lane = threadIdx.x & 63;
    int n = blockIdx.x * 4 + wave;
    if (n >= NN) return;
    int head = lane >> 4, j = lane & 15;
    const float* qp = q + (size_t)n * 128 + head * 32;
    const float* wp = We + j * 128 + head * 32;
    float acc = 0.f;
    #pragma unroll
    for (int c = 0; c < 32; c += 4) {
        float4 qv = *(const float4*)(qp + c);
        float4 wv = *(const float4*)(wp + c);
        acc += qv.x * wv.x + qv.y * wv.y + qv.z * wv.z + qv.w * wv.w;
    }
    qweb[(size_t)n * 64 + lane] = acc * 0.17677669529663687f;  // 1/sqrt(32) folded
}

// ---------------- CSR build ----------------
__global__ __launch_bounds__(256) void hist_k(const int* __restrict__ dst, int* __restrict__ deg) {
    int e = blockIdx.x * 256 + threadIdx.x;
    if (e < EE) atomicAdd(&deg[dst[e]], 1);
}

__global__ __launch_bounds__(256) void scan_phaseA(const int* __restrict__ deg, int* __restrict__ rs,
                                                   int* __restrict__ bsum) {
    __shared__ int sm[256];
    int tid = threadIdx.x;
    int i = blockIdx.x * 256 + tid;
    int v = (i < NN) ? deg[i] : 0;
    sm[tid] = v;
    __syncthreads();
    #pragma unroll
    for (int off = 1; off < 256; off <<= 1) {
        int t = 0;
        if (tid >= off) t = sm[tid - off];
        __syncthreads();
        if (tid >= off) sm[tid] += t;
        __syncthreads();
    }
    if (i < NN) rs[i] = sm[tid] - v;
    if (tid == 255) bsum[blockIdx.x] = sm[255];
}

__global__ __launch_bounds__(256) void scan_phaseB(int* __restrict__ bsum, int nb) {
    __shared__ int sm[256];
    int tid = threadIdx.x;
    int v = (tid < nb) ? bsum[tid] : 0;
    sm[tid] = v;
    __syncthreads();
    #pragma unroll
    for (int off = 1; off < 256; off <<= 1) {
        int t = 0;
        if (tid >= off) t = sm[tid - off];
        __syncthreads();
        if (tid >= off) sm[tid] += t;
        __syncthreads();
    }
    if (tid < nb) bsum[tid] = sm[tid] - v;
}

__global__ __launch_bounds__(256) void scan_phaseC(int* __restrict__ rs, const int* __restrict__ bsum) {
    int i = blockIdx.x * 256 + threadIdx.x;
    if (i < NN) rs[i] += bsum[blockIdx.x];
    if (i == 0) rs[NN] = EE;
}

__global__ __launch_bounds__(256) void scatter_k(
    const int* __restrict__ src, const int* __restrict__ dst,
    const float* __restrict__ eattr, const int* __restrict__ rs,
    int* __restrict__ cur, int* __restrict__ srcs_sorted,
    unsigned short* __restrict__ eas)
{
    int e = blockIdx.x * 256 + threadIdx.x;
    if (e < EE) {
        int d = dst[e];
        int p = atomicAdd(&cur[d], 1);
        int pos = rs[d] + p;
        srcs_sorted[pos] = src[e];
        const float* ap = eattr + (size_t)e * 16;
        float4 a0 = *(const float4*)ap;
        float4 a1 = *(const float4*)(ap + 4);
        float4 a2 = *(const float4*)(ap + 8);
        float4 a3 = *(const float4*)(ap + 12);
        us8 lo, hi;
        lo[0] = f2bf(a0.x); lo[1] = f2bf(a0.y); lo[2] = f2bf(a0.z); lo[3] = f2bf(a0.w);
        lo[4] = f2bf(a1.x); lo[5] = f2bf(a1.y); lo[6] = f2bf(a1.z); lo[7] = f2bf(a1.w);
        hi[0] = f2bf(a2.x); hi[1] = f2bf(a2.y); hi[2] = f2bf(a2.z); hi[3] = f2bf(a2.w);
        hi[4] = f2bf(a3.x); hi[5] = f2bf(a3.y); hi[6] = f2bf(a3.z); hi[7] = f2bf(a3.w);
        *(us8*)(eas + (size_t)pos * 16)     = lo;
        *(us8*)(eas + (size_t)pos * 16 + 8) = hi;
    }
}

// ---------------- fused attention + beta gate + LN1 ----------------
// R7: DPP row reductions (no LDS shuffles in the edge loop), qwe precomputed,
// zero-waste rolling double-buffer with wave-uniform tail branches.
__global__ __launch_bounds__(256, 4) void attn_kernel(
    const float* __restrict__ q, const unsigned int* __restrict__ kvb,
    const float* __restrict__ xr, const float* __restrict__ x,
    const unsigned short* __restrict__ eas, const int* __restrict__ srcs,
    const int* __restrict__ rs, const float* __restrict__ qweb,
    const float* __restrict__ We, const float* __restrict__ be,
    const float* __restrict__ Wbeta,
    const float* __restrict__ gamma1, const float* __restrict__ beta1,
    float* __restrict__ hout, unsigned int* __restrict__ hbf)
{
    int wave = threadIdx.x >> 6;
    int lane = threadIdx.x & 63;
    int n = blockIdx.x * 4 + wave;
    if (n >= NN) return;
    int c0 = lane * 2, c1 = c0 + 1;
    int jlane = lane & 15;
    int hbase = lane & 48;

    float be0 = be[c0], be1 = be[c1];

    float2 q2 = *(const float2*)(q + (size_t)n * 128 + c0);
    q2.x *= 0.17677669529663687f;
    q2.y *= 0.17677669529663687f;

    float qbe = q2.x * be0 + q2.y * be1;
    RED16(qbe);
    float qwe = qweb[(size_t)n * 64 + lane];

    float l = 0.f, a0 = 0.f, a1 = 0.f, s = 0.f;
    int beg = rs[n], end = rs[n + 1];

    int sr0[8], sr1[8];
    unsigned short ea0[8], ea1[8];
    uint2 kv0[8], kv1[8];

#define LOADMETA(g, SR, EA) { \
    _Pragma("unroll") \
    for (int j = 0; j < 8; j++) { \
        int idx = min((g) + j, EE - 1); \
        SR[j] = srcs[idx]; \
        EA[j] = eas[(size_t)idx * 16 + jlane]; \
    } }
#define GATHER(SR, KV) { \
    _Pragma("unroll") \
    for (int j = 0; j < 8; j++) \
        KV[j] = *(const uint2*)(kvb + (size_t)SR[j] * 128 + (lane << 1)); }
#define COMPUTE(g, EA, KV) { \
    int cnt = end - (g); \
    _Pragma("unroll") \
    for (int j = 0; j < 8; j++) { \
        if (j < cnt) { \
            float ea = bf2f(EA[j]); \
            unsigned int kx = KV[j].x, ky = KV[j].y; \
            float k0 = __uint_as_float(kx << 16); \
            float v0 = __uint_as_float(kx & 0xffff0000u); \
            float k1 = __uint_as_float(ky << 16); \
            float v1 = __uint_as_float(ky & 0xffff0000u); \
            float part = fmaf(q2.x, k0, fmaf(q2.y, k1, qwe * ea)); \
            RED16(part); \
            float wgt = __expf(part + qbe); \
            l += wgt; \
            a0 = fmaf(wgt, v0, a0); \
            a1 = fmaf(wgt, v1, a1); \
            s = fmaf(wgt, ea, s); \
        } } }

    if (beg < end) {
        LOADMETA(beg, sr0, ea0)
        GATHER(sr0, kv0)
        for (int g = beg; ; g += 16) {
            bool m1 = (g + 8 < end);
            if (m1) { LOADMETA(g + 8, sr1, ea1) GATHER(sr1, kv1) }
            COMPUTE(g, ea0, kv0)
            if (!m1) break;
            bool m2 = (g + 16 < end);
            if (m2) { LOADMETA(g + 16, sr0, ea0) GATHER(sr0, kv0) }
            COMPUTE(g + 8, ea1, kv1)
            if (!m2) break;
        }
    }
#undef LOADMETA
#undef GATHER
#undef COMPUTE

    // e-contribution: (sum wgt*eattr)@We + l*be
    float eo0 = l * be0, eo1 = l * be1;
    #pragma unroll
    for (int j = 0; j < 16; j++) {
        float sj = __shfl(s, hbase + j);
        eo0 = fmaf(sj, We[j * 128 + c0], eo0);
        eo1 = fmaf(sj, We[j * 128 + c1], eo1);
    }
    a0 += eo0; a1 += eo1;

    float inv = l > 0.f ? 1.f / l : 0.f;
    float o0 = a0 * inv, o1 = a1 * inv;

    float wbo0 = Wbeta[c0],        wbo1 = Wbeta[c1];
    float wbx0 = Wbeta[128 + c0],  wbx1 = Wbeta[128 + c1];
    float wbd0 = Wbeta[256 + c0],  wbd1 = Wbeta[256 + c1];
    float2 xr2 = *(const float2*)(xr + (size_t)n * 128 + c0);
    float bl = o0 * wbo0 + o1 * wbo1 + xr2.x * wbx0 + xr2.y * wbx1
             + (o0 - xr2.x) * wbd0 + (o1 - xr2.y) * wbd1;
    #pragma unroll
    for (int off = 1; off < 64; off <<= 1) bl += __shfl_xor(bl, off);
    float beta = 1.f / (1.f + __expf(-bl));
    float xs0 = beta * xr2.x + (1.f - beta) * o0;
    float xs1 = beta * xr2.y + (1.f - beta) * o1;

    float2 xv = *(const float2*)(x + (size_t)n * 128 + c0);
    float t0 = xv.x + xs0, t1 = xv.y + xs1;
    float sm = t0 + t1;
    #pragma unroll
    for (int off = 1; off < 64; off <<= 1) sm += __shfl_xor(sm, off);
    float mu = sm * (1.f / 128.f);
    float d0 = t0 - mu, d1 = t1 - mu;
    float vv = d0 * d0 + d1 * d1;
    #pragma unroll
    for (int off = 1; off < 64; off <<= 1) vv += __shfl_xor(vv, off);
    float is = rsqrtf(vv * (1.f / 128.f) + 1e-5f);
    float h0 = d0 * is * gamma1[c0] + beta1[c0];
    float h1 = d1 * is * gamma1[c1] + beta1[c1];
    *(float2*)(hout + (size_t)n * 128 + c0) = make_float2(h0, h1);
    hbf[(size_t)n * 64 + lane] = (unsigned int)f2bf(h0) | ((unsigned int)f2bf(h1) << 16);
}

// ---------------- final LN over h + ff2 ----------------
__global__ __launch_bounds__(256) void ln2_k(
    const float* __restrict__ h, const float* __restrict__ ff2,
    const float* __restrict__ gamma2, const float* __restrict__ beta2,
    float* __restrict__ out)
{
    int wave = threadIdx.x >> 6;
    int lane = threadIdx.x & 63;
    int n = blockIdx.x * 4 + wave;
    if (n >= NN) return;
    int c0 = lane * 2;
    float2 hv = *(const float2*)(h + (size_t)n * 128 + c0);
    float2 fv = *(const float2*)(ff2 + (size_t)n * 128 + c0);
    float t0 = hv.x + fv.x, t1 = hv.y + fv.y;
    float sm = t0 + t1;
    #pragma unroll
    for (int off = 1; off < 64; off <<= 1) sm += __shfl_xor(sm, off);
    float mu = sm * (1.f / 128.f);
    float d0 = t0 - mu, d1 = t1 - mu;
    float vv = d0 * d0 + d1 * d1;
    #pragma unroll
    for (int off = 1; off < 64; off <<= 1) vv += __shfl_xor(vv, off);
    float is = rsqrtf(vv * (1.f / 128.f) + 1e-5f);
    float o0 = d0 * is * gamma2[c0] + beta2[c0];
    float o1 = d1 * is * gamma2[c0 + 1] + beta2[c0 + 1];
    *(float2*)(out + (size_t)n * 128 + c0) = make_float2(o0, o1);
}

extern "C" void kernel_launch(void* const* d_in, const int* in_sizes, int n_in,
                              void* d_out, int out_size, void* d_ws, size_t ws_size,
                              hipStream_t stream) {
    const float* x      = (const float*)d_in[0];
    const int*   eindex = (const int*)d_in[1];
    const float* eattr  = (const float*)d_in[2];
    const float* Wq = (const float*)d_in[3];  const float* bq = (const float*)d_in[4];
    const float* Wk = (const float*)d_in[5];  const float* bk = (const float*)d_in[6];
    const float* Wv = (const float*)d_in[7];  const float* bv = (const float*)d_in[8];
    const float* We = (const float*)d_in[9];  const float* be = (const float*)d_in[10];
    const float* Ws = (const float*)d_in[11]; const float* bs = (const float*)d_in[12];
    const float* Wbeta = (const float*)d_in[13];
    const float* g1 = (const float*)d_in[14]; const float* b1 = (const float*)d_in[15];
    const float* Wf1 = (const float*)d_in[16]; const float* bf1 = (const float*)d_in[17];
    const float* Wf2 = (const float*)d_in[18]; const float* bf2 = (const float*)d_in[19];
    const float* g2 = (const float*)d_in[20]; const float* b2 = (const float*)d_in[21];

    char* ws = (char*)d_ws;
    size_t off = 0;
    #define ALLOC(ptr, type, bytes) type* ptr = (type*)(ws + off); off = (off + (size_t)(bytes) + 255) & ~(size_t)255;
    ALLOC(wqkvsT, unsigned short, 512 * 128 * 2)
    ALLOC(wf1T,   unsigned short, 512 * 128 * 2)
    ALLOC(wf2T,   unsigned short, 128 * 512 * 2)
    ALLOC(biasq,  float,          512 * 4)
    ALLOC(qb,     float,          (size_t)NN * 128 * 4)     // 25.6 MB
    ALLOC(kvb,    unsigned short, (size_t)NN * 256 * 2)     // 25.6 MB (ff1 overlays qb+kvb)
    ALLOC(xrb,    float,          (size_t)NN * 128 * 4)     // 25.6 MB (ff2 overlays)
    ALLOC(h,      float,          (size_t)NN * 128 * 4)     // 25.6 MB
    ALLOC(hbf,    unsigned int,   (size_t)NN * 128 * 2)     // 12.8 MB
    ALLOC(qweb,   float,          (size_t)NN * 64 * 4)      // 12.8 MB
    ALLOC(deg,    int,            2 * NN * 4)               // deg[NN]+cursor[NN], one region
    ALLOC(row_start, int,         (NN + 1) * 4)
    ALLOC(bsum,   int,            1024)
    ALLOC(srcs_sorted, int,       (size_t)EE * 4)           // 3.2 MB
    ALLOC(eas,    unsigned short, (size_t)EE * 16 * 2)      // 25.6 MB
    #undef ALLOC
    int* cursor = deg + NN;
    unsigned short* ff1 = (unsigned short*)qb;
    float* ff2 = xrb;

    hipMemsetAsync(deg, 0, (size_t)2 * NN * 4, stream);

    pack_w<<<770, 256, 0, stream>>>(Wq, Wk, Wv, Ws, bq, bk, bv, bs, Wf1, Wf2,
                                    wqkvsT, wf1T, wf2T, biasq);

    // q|k|v|xr projections with split epilogue (128x128 tiles)
    gemm_k<false, 2><<<391 * 4, 256, 0, stream>>>(x, wqkvsT, biasq, nullptr,
                                                  qb, kvb, xrb, NN, 512, 128);

    // per-node qwe table
    qwe_k<<<12500, 256, 0, stream>>>(qb, We, qweb);

    // CSR by dst + permuted src/eattr
    hist_k<<<3125, 256, 0, stream>>>(eindex + EE, deg);
    scan_phaseA<<<196, 256, 0, stream>>>(deg, row_start, bsum);
    scan_phaseB<<<1, 256, 0, stream>>>(bsum, 196);
    scan_phaseC<<<196, 256, 0, stream>>>(row_start, bsum);
    scatter_k<<<3125, 256, 0, stream>>>(eindex, eindex + EE, eattr, row_start,
                                        cursor, srcs_sorted, eas);

    // fused attention + beta gate + residual + LN1
    attn_kernel<<<12500, 256, 0, stream>>>(qb, (const unsigned int*)kvb, xrb, x,
                                           eas, srcs_sorted, row_start, qweb,
                                           We, be, Wbeta, g1, b1, h, hbf);

    // FFN
    gemm_k<true, 1><<<391 * 4, 256, 0, stream>>>(hbf, wf1T, bf1, ff1,
                                                 nullptr, nullptr, nullptr, NN, 512, 128);
    gemm_k<true, 0><<<391 * 1, 256, 0, stream>>>(ff1, wf2T, bf2, ff2,
                                                 nullptr, nullptr, nullptr, NN, 128, 512);

    // final LN
    ln2_k<<<12500, 256, 0, stream>>>(h, ff2, g2, b2, (float*)d_out);
}

// Round 8
// 497.772 us; speedup vs baseline: 1.0681x; 1.0524x over previous
//
#include <hip/hip_runtime.h>
#include <hip/hip_bf16.h>

#define NN 50000
#define EE 800000
#define DIMM 128

typedef __attribute__((ext_vector_type(8))) short bf16x8;
typedef __attribute__((ext_vector_type(8))) unsigned short us8;
typedef __attribute__((ext_vector_type(4))) float f32x4;

static __device__ __forceinline__ unsigned short f2bf(float f) {
    unsigned int u = __float_as_uint(f);
    unsigned int r = (u + 0x7fffu + ((u >> 16) & 1u)) >> 16;
    return (unsigned short)r;
}
static __device__ __forceinline__ float bf2f(unsigned short s) {
    return __uint_as_float(((unsigned int)s) << 16);
}

// sum across the 16-lane DPP row — full-rate VALU, no LDS
#define RED16(v) do { int _t; \
    _t = __builtin_amdgcn_update_dpp(0, __float_as_int(v), 0x128, 0xF, 0xF, true); v += __int_as_float(_t); \
    _t = __builtin_amdgcn_update_dpp(0, __float_as_int(v), 0x124, 0xF, 0xF, true); v += __int_as_float(_t); \
    _t = __builtin_amdgcn_update_dpp(0, __float_as_int(v), 0x122, 0xF, 0xF, true); v += __int_as_float(_t); \
    _t = __builtin_amdgcn_update_dpp(0, __float_as_int(v), 0x121, 0xF, 0xF, true); v += __int_as_float(_t); \
} while (0)

#define QSCALE 0.17677669529663687f   // 1/sqrt(32)

// ---------------- weight packing ----------------
// wqkvsT[640][128]: rows 0-511 = Wq|Wk|Wv|Ws cols; 512-575 = Wq@P (qwe);
// 576-579 = Wq@be (qbe); 580-639 = 0.  biasq[640] matches.
__global__ __launch_bounds__(256) void pack_w(
    const float* __restrict__ Wq, const float* __restrict__ Wk,
    const float* __restrict__ Wv, const float* __restrict__ Ws,
    const float* __restrict__ bq, const float* __restrict__ bk,
    const float* __restrict__ bv, const float* __restrict__ bs,
    const float* __restrict__ Wf1, const float* __restrict__ Wf2,
    const float* __restrict__ We, const float* __restrict__ be,
    unsigned short* __restrict__ wqkvsT, unsigned short* __restrict__ wf1T,
    unsigned short* __restrict__ wf2T, float* __restrict__ biasq)
{
    int i = blockIdx.x * 256 + threadIdx.x;
    if (i < 81920) {                        // wqkvsT[n][k], n in [0,640)
        int n = i >> 7, k = i & 127;
        unsigned short outv = 0;
        if (n < 512) {
            int sel = n >> 7, col = n & 127;
            const float* W = sel == 0 ? Wq : sel == 1 ? Wk : sel == 2 ? Wv : Ws;
            outv = f2bf(W[k * 128 + col]);
        } else if (n < 576) {
            int m = n - 512, head = m >> 4, j = m & 15;
            float acc = 0.f;
            for (int c = 0; c < 32; c++)
                acc += Wq[k * 128 + head * 32 + c] * We[j * 128 + head * 32 + c];
            outv = f2bf(acc * QSCALE);
        } else if (n < 580) {
            int head = n - 576;
            float acc = 0.f;
            for (int c = 0; c < 32; c++)
                acc += Wq[k * 128 + head * 32 + c] * be[head * 32 + c];
            outv = f2bf(acc * QSCALE);
        }
        wqkvsT[i] = outv;
    } else if (i < 147456) {                // wf1T[n][k]
        int j = i - 81920; int n = j >> 7, k = j & 127;
        wf1T[j] = f2bf(Wf1[k * 512 + n]);
    } else if (i < 212992) {                // wf2T[n][k]
        int j = i - 147456; int n = j >> 9, k = j & 511;
        wf2T[j] = f2bf(Wf2[k * 128 + n]);
    } else if (i < 213632) {                // biasq[640]
        int j = i - 212992;
        float bvv = 0.f;
        if (j < 512) {
            int sel = j >> 7;
            const float* bp = sel == 0 ? bq : sel == 1 ? bk : sel == 2 ? bv : bs;
            bvv = bp[j & 127];
        } else if (j < 576) {
            int m = j - 512, head = m >> 4, jj = m & 15;
            float acc = 0.f;
            for (int c = 0; c < 32; c++)
                acc += bq[head * 32 + c] * We[jj * 128 + head * 32 + c];
            bvv = acc * QSCALE;
        } else if (j < 580) {
            int head = j - 576;
            float acc = 0.f;
            for (int c = 0; c < 32; c++)
                acc += bq[head * 32 + c] * be[head * 32 + c];
            bvv = acc * QSCALE;
        }
        biasq[j] = bvv;
    }
}

// ---------------- bf16 MFMA GEMM, 128x128 tile ----------------
// EPI 0: fp32 out + bias.  EPI 1: relu -> bf16 out + bias.
// EPI 2: qkvs split (q fp32 | kv bf16 interleaved | xr fp32 | qwe/qbe fp32).
// EPI 3: ffn2 + residual(h) + LayerNorm fused -> d_out.
template<bool A_BF16, int EPI>
__global__ __launch_bounds__(256) void gemm_k(
    const void* __restrict__ Ap, const unsigned short* __restrict__ Bt,
    const float* __restrict__ bias, void* __restrict__ Cp,
    float* __restrict__ qb, unsigned short* __restrict__ kvb, float* __restrict__ xrb,
    float* __restrict__ qweb, float* __restrict__ qbeb,
    const float* __restrict__ hb, const float* __restrict__ g2, const float* __restrict__ b2,
    int M, int Nn, int K)
{
    __shared__ unsigned short As[128][72];
    __shared__ unsigned short Bs[128][72];
    __shared__ float lsum[2][128];
    __shared__ float lsq[2][128];
    int tid = threadIdx.x;
    int nb = Nn >> 7;
    int bm = blockIdx.x / nb, bn = blockIdx.x % nb;
    int w = tid >> 6, lane = tid & 63;
    int wm = w >> 1, wn = w & 1;
    int lr = lane & 15, quad = lane >> 4;

    f32x4 acc[4][4];
    #pragma unroll
    for (int i = 0; i < 4; i++)
        #pragma unroll
        for (int j = 0; j < 4; j++) { f32x4 z = {0.f, 0.f, 0.f, 0.f}; acc[i][j] = z; }

    for (int kc = 0; kc < K; kc += 64) {
        #pragma unroll
        for (int it = 0; it < 4; ++it) {
            int row = it * 32 + (tid >> 3);
            int k8 = (tid & 7) * 8;
            int rg = bm * 128 + row;
            us8 st = {0, 0, 0, 0, 0, 0, 0, 0};
            if (rg < M) {
                if constexpr (A_BF16) {
                    st = *(const us8*)((const unsigned short*)Ap + (size_t)rg * K + kc + k8);
                } else {
                    const float* src = (const float*)Ap + (size_t)rg * K + kc + k8;
                    float4 f0 = *(const float4*)src;
                    float4 f1 = *(const float4*)(src + 4);
                    st[0] = f2bf(f0.x); st[1] = f2bf(f0.y); st[2] = f2bf(f0.z); st[3] = f2bf(f0.w);
                    st[4] = f2bf(f1.x); st[5] = f2bf(f1.y); st[6] = f2bf(f1.z); st[7] = f2bf(f1.w);
                }
            }
            *(us8*)&As[row][k8] = st;
            *(us8*)&Bs[row][k8] = *(const us8*)(Bt + (size_t)(bn * 128 + row) * K + kc + k8);
        }
        __syncthreads();
        #pragma unroll
        for (int kk = 0; kk < 2; ++kk) {
            bf16x8 af[4], bfr[4];
            #pragma unroll
            for (int mi = 0; mi < 4; mi++)
                af[mi] = *(const bf16x8*)&As[wm * 64 + mi * 16 + lr][kk * 32 + quad * 8];
            #pragma unroll
            for (int ni = 0; ni < 4; ni++)
                bfr[ni] = *(const bf16x8*)&Bs[wn * 64 + ni * 16 + lr][kk * 32 + quad * 8];
            #pragma unroll
            for (int mi = 0; mi < 4; mi++)
                #pragma unroll
                for (int ni = 0; ni < 4; ni++)
                    acc[mi][ni] = __builtin_amdgcn_mfma_f32_16x16x32_bf16(af[mi], bfr[ni], acc[mi][ni], 0, 0, 0);
        }
        __syncthreads();
    }

    if constexpr (EPI == 3) {
        // fused residual + LayerNorm epilogue (Nn == 128: block owns full rows)
        #pragma unroll
        for (int mi = 0; mi < 4; mi++) {
            #pragma unroll
            for (int ni = 0; ni < 4; ni++) {
                int cg = wn * 64 + ni * 16 + lr;
                float bv = bias[cg];
                #pragma unroll
                for (int r = 0; r < 4; r++) {
                    int rg = bm * 128 + wm * 64 + mi * 16 + quad * 4 + r;
                    float hv = (rg < M) ? hb[(size_t)rg * 128 + cg] : 0.f;
                    acc[mi][ni][r] += bv + hv;       // t = ff2 + bias + h
                }
            }
        }
        float prs[4][4], prq[4][4];
        #pragma unroll
        for (int mi = 0; mi < 4; mi++)
            #pragma unroll
            for (int r = 0; r < 4; r++) {
                float sm = 0.f, sq = 0.f;
                #pragma unroll
                for (int ni = 0; ni < 4; ni++) {
                    float t = acc[mi][ni][r];
                    sm += t; sq += t * t;
                }
                RED16(sm); RED16(sq);
                prs[mi][r] = sm; prq[mi][r] = sq;
            }
        if (lr == 0) {
            #pragma unroll
            for (int mi = 0; mi < 4; mi++)
                #pragma unroll
                for (int r = 0; r < 4; r++) {
                    int row = wm * 64 + mi * 16 + quad * 4 + r;
                    lsum[wn][row] = prs[mi][r];
                    lsq[wn][row]  = prq[mi][r];
                }
        }
        __syncthreads();
        float* outp = (float*)Cp;
        #pragma unroll
        for (int mi = 0; mi < 4; mi++) {
            #pragma unroll
            for (int ni = 0; ni < 4; ni++) {
                int cg = wn * 64 + ni * 16 + lr;
                float gv = g2[cg], bv2 = b2[cg];
                #pragma unroll
                for (int r = 0; r < 4; r++) {
                    int row = wm * 64 + mi * 16 + quad * 4 + r;
                    int rg = bm * 128 + row;
                    if (rg < M) {
                        float tot = lsum[0][row] + lsum[1][row];
                        float tq  = lsq[0][row] + lsq[1][row];
                        float mu = tot * (1.f / 128.f);
                        float var = tq * (1.f / 128.f) - mu * mu;
                        float is = rsqrtf(var + 1e-5f);
                        outp[(size_t)rg * 128 + cg] = (acc[mi][ni][r] - mu) * is * gv + bv2;
                    }
                }
            }
        }
        return;
    }

    #pragma unroll
    for (int mi = 0; mi < 4; mi++) {
        #pragma unroll
        for (int ni = 0; ni < 4; ni++) {
            int cg = bn * 128 + wn * 64 + ni * 16 + lr;
            float bv = bias[cg];
            #pragma unroll
            for (int r = 0; r < 4; r++) {
                int rg = bm * 128 + wm * 64 + mi * 16 + quad * 4 + r;
                if (rg < M) {
                    float val = acc[mi][ni][r] + bv;
                    if constexpr (EPI == 0) {
                        ((float*)Cp)[(size_t)rg * Nn + cg] = val;
                    } else if constexpr (EPI == 1) {
                        val = fmaxf(val, 0.f);
                        ((unsigned short*)Cp)[(size_t)rg * Nn + cg] = f2bf(val);
                    } else {
                        int sel = cg >> 7, c = cg & 127;
                        if (sel == 0)      qb[(size_t)rg * 128 + c] = val;
                        else if (sel == 1) kvb[(size_t)rg * 256 + 2 * c] = f2bf(val);
                        else if (sel == 2) kvb[(size_t)rg * 256 + 2 * c + 1] = f2bf(val);
                        else if (sel == 3) xrb[(size_t)rg * 128 + c] = val;
                        else {
                            if (c < 64)      qweb[(size_t)rg * 64 + c] = val;
                            else if (c < 68) qbeb[(size_t)rg * 4 + (c - 64)] = val;
                        }
                    }
                }
            }
        }
    }
}

// ---------------- CSR build ----------------
__global__ __launch_bounds__(256) void hist_k(const int* __restrict__ dst, int* __restrict__ deg) {
    int e = blockIdx.x * 256 + threadIdx.x;
    if (e < EE) atomicAdd(&deg[dst[e]], 1);
}

__global__ __launch_bounds__(256) void scan_phaseA(const int* __restrict__ deg, int* __restrict__ rs,
                                                   int* __restrict__ bsum) {
    __shared__ int sm[256];
    int tid = threadIdx.x;
    int i = blockIdx.x * 256 + tid;
    int v = (i < NN) ? deg[i] : 0;
    sm[tid] = v;
    __syncthreads();
    #pragma unroll
    for (int off = 1; off < 256; off <<= 1) {
        int t = 0;
        if (tid >= off) t = sm[tid - off];
        __syncthreads();
        if (tid >= off) sm[tid] += t;
        __syncthreads();
    }
    if (i < NN) rs[i] = sm[tid] - v;
    if (tid == 255) bsum[blockIdx.x] = sm[255];
}

__global__ __launch_bounds__(256) void scan_phaseB(int* __restrict__ bsum, int nb) {
    __shared__ int sm[256];
    int tid = threadIdx.x;
    int v = (tid < nb) ? bsum[tid] : 0;
    sm[tid] = v;
    __syncthreads();
    #pragma unroll
    for (int off = 1; off < 256; off <<= 1) {
        int t = 0;
        if (tid >= off) t = sm[tid - off];
        __syncthreads();
        if (tid >= off) sm[tid] += t;
        __syncthreads();
    }
    if (tid < nb) bsum[tid] = sm[tid] - v;
}

__global__ __launch_bounds__(256) void scan_phaseC(int* __restrict__ rs, const int* __restrict__ bsum) {
    int i = blockIdx.x * 256 + threadIdx.x;
    if (i < NN) rs[i] += bsum[blockIdx.x];
    if (i == 0) rs[NN] = EE;
}

__global__ __launch_bounds__(256) void scatter_k(
    const int* __restrict__ src, const int* __restrict__ dst,
    const float* __restrict__ eattr, const int* __restrict__ rs,
    int* __restrict__ cur, int* __restrict__ srcs_sorted,
    unsigned short* __restrict__ eas)
{
    int e = blockIdx.x * 256 + threadIdx.x;
    if (e < EE) {
        int d = dst[e];
        int p = atomicAdd(&cur[d], 1);
        int pos = rs[d] + p;
        srcs_sorted[pos] = src[e];
        const float* ap = eattr + (size_t)e * 16;
        float4 a0 = *(const float4*)ap;
        float4 a1 = *(const float4*)(ap + 4);
        float4 a2 = *(const float4*)(ap + 8);
        float4 a3 = *(const float4*)(ap + 12);
        us8 lo, hi;
        lo[0] = f2bf(a0.x); lo[1] = f2bf(a0.y); lo[2] = f2bf(a0.z); lo[3] = f2bf(a0.w);
        lo[4] = f2bf(a1.x); lo[5] = f2bf(a1.y); lo[6] = f2bf(a1.z); lo[7] = f2bf(a1.w);
        hi[0] = f2bf(a2.x); hi[1] = f2bf(a2.y); hi[2] = f2bf(a2.z); hi[3] = f2bf(a2.w);
        hi[4] = f2bf(a3.x); hi[5] = f2bf(a3.y); hi[6] = f2bf(a3.z); hi[7] = f2bf(a3.w);
        *(us8*)(eas + (size_t)pos * 16)     = lo;
        *(us8*)(eas + (size_t)pos * 16 + 8) = hi;
    }
}

// ---------------- fused attention + beta gate + LN1 ----------------
__global__ __launch_bounds__(256, 4) void attn_kernel(
    const float* __restrict__ q, const unsigned int* __restrict__ kvb,
    const float* __restrict__ xr, const float* __restrict__ x,
    const unsigned short* __restrict__ eas, const int* __restrict__ srcs,
    const int* __restrict__ rs, const float* __restrict__ qweb,
    const float* __restrict__ qbeb,
    const float* __restrict__ We, const float* __restrict__ be,
    const float* __restrict__ Wbeta,
    const float* __restrict__ gamma1, const float* __restrict__ beta1,
    float* __restrict__ hout, unsigned int* __restrict__ hbf)
{
    int wave = threadIdx.x >> 6;
    int lane = threadIdx.x & 63;
    int n = blockIdx.x * 4 + wave;
    if (n >= NN) return;
    int c0 = lane * 2, c1 = c0 + 1;
    int jlane = lane & 15;
    int hbase = lane & 48;

    float2 q2 = *(const float2*)(q + (size_t)n * 128 + c0);
    q2.x *= QSCALE;
    q2.y *= QSCALE;

    float qwe = qweb[(size_t)n * 64 + lane];
    float qbe = qbeb[(size_t)n * 4 + (lane >> 4)];

    float l = 0.f, a0 = 0.f, a1 = 0.f, s = 0.f;
    int beg = rs[n], end = rs[n + 1];

    int sr0[8], sr1[8];
    unsigned short ea0[8], ea1[8];
    uint2 kv0[8], kv1[8];

#define LOADMETA(g, SR, EA) { \
    _Pragma("unroll") \
    for (int j = 0; j < 8; j++) { \
        int idx = min((g) + j, EE - 1); \
        SR[j] = srcs[idx]; \
        EA[j] = eas[(size_t)idx * 16 + jlane]; \
    } }
#define GATHER(SR, KV) { \
    _Pragma("unroll") \
    for (int j = 0; j < 8; j++) \
        KV[j] = *(const uint2*)(kvb + (size_t)SR[j] * 128 + (lane << 1)); }
#define COMPUTE(g, EA, KV) { \
    int cnt = end - (g); \
    _Pragma("unroll") \
    for (int j = 0; j < 8; j++) { \
        if (j < cnt) { \
            float ea = bf2f(EA[j]); \
            unsigned int kx = KV[j].x, ky = KV[j].y; \
            float k0 = __uint_as_float(kx << 16); \
            float v0 = __uint_as_float(kx & 0xffff0000u); \
            float k1 = __uint_as_float(ky << 16); \
            float v1 = __uint_as_float(ky & 0xffff0000u); \
            float part = fmaf(q2.x, k0, fmaf(q2.y, k1, qwe * ea)); \
            RED16(part); \
            float wgt = __expf(part + qbe); \
            l += wgt; \
            a0 = fmaf(wgt, v0, a0); \
            a1 = fmaf(wgt, v1, a1); \
            s = fmaf(wgt, ea, s); \
        } } }

    if (beg < end) {
        LOADMETA(beg, sr0, ea0)
        GATHER(sr0, kv0)
        for (int g = beg; ; g += 16) {
            bool m1 = (g + 8 < end);
            if (m1) { LOADMETA(g + 8, sr1, ea1) GATHER(sr1, kv1) }
            COMPUTE(g, ea0, kv0)
            if (!m1) break;
            bool m2 = (g + 16 < end);
            if (m2) { LOADMETA(g + 16, sr0, ea0) GATHER(sr0, kv0) }
            COMPUTE(g + 8, ea1, kv1)
            if (!m2) break;
        }
    }
#undef LOADMETA
#undef GATHER
#undef COMPUTE

    // e-contribution: (sum wgt*eattr)@We + l*be
    float be0 = be[c0], be1 = be[c1];
    float eo0 = l * be0, eo1 = l * be1;
    #pragma unroll
    for (int j = 0; j < 16; j++) {
        float sj = __shfl(s, hbase + j);
        eo0 = fmaf(sj, We[j * 128 + c0], eo0);
        eo1 = fmaf(sj, We[j * 128 + c1], eo1);
    }
    a0 += eo0; a1 += eo1;

    float inv = l > 0.f ? 1.f / l : 0.f;
    float o0 = a0 * inv, o1 = a1 * inv;

    float wbo0 = Wbeta[c0],        wbo1 = Wbeta[c1];
    float wbx0 = Wbeta[128 + c0],  wbx1 = Wbeta[128 + c1];
    float wbd0 = Wbeta[256 + c0],  wbd1 = Wbeta[256 + c1];
    float2 xr2 = *(const float2*)(xr + (size_t)n * 128 + c0);
    float bl = o0 * wbo0 + o1 * wbo1 + xr2.x * wbx0 + xr2.y * wbx1
             + (o0 - xr2.x) * wbd0 + (o1 - xr2.y) * wbd1;
    #pragma unroll
    for (int off = 1; off < 64; off <<= 1) bl += __shfl_xor(bl, off);
    float beta = 1.f / (1.f + __expf(-bl));
    float xs0 = beta * xr2.x + (1.f - beta) * o0;
    float xs1 = beta * xr2.y + (1.f - beta) * o1;

    float2 xv = *(const float2*)(x + (size_t)n * 128 + c0);
    float t0 = xv.x + xs0, t1 = xv.y + xs1;
    float sm = t0 + t1;
    #pragma unroll
    for (int off = 1; off < 64; off <<= 1) sm += __shfl_xor(sm, off);
    float mu = sm * (1.f / 128.f);
    float d0 = t0 - mu, d1 = t1 - mu;
    float vv = d0 * d0 + d1 * d1;
    #pragma unroll
    for (int off = 1; off < 64; off <<= 1) vv += __shfl_xor(vv, off);
    float is = rsqrtf(vv * (1.f / 128.f) + 1e-5f);
    float h0 = d0 * is * gamma1[c0] + beta1[c0];
    float h1 = d1 * is * gamma1[c1] + beta1[c1];
    *(float2*)(hout + (size_t)n * 128 + c0) = make_float2(h0, h1);
    hbf[(size_t)n * 64 + lane] = (unsigned int)f2bf(h0) | ((unsigned int)f2bf(h1) << 16);
}

extern "C" void kernel_launch(void* const* d_in, const int* in_sizes, int n_in,
                              void* d_out, int out_size, void* d_ws, size_t ws_size,
                              hipStream_t stream) {
    const float* x      = (const float*)d_in[0];
    const int*   eindex = (const int*)d_in[1];
    const float* eattr  = (const float*)d_in[2];
    const float* Wq = (const float*)d_in[3];  const float* bq = (const float*)d_in[4];
    const float* Wk = (const float*)d_in[5];  const float* bk = (const float*)d_in[6];
    const float* Wv = (const float*)d_in[7];  const float* bv = (const float*)d_in[8];
    const float* We = (const float*)d_in[9];  const float* be = (const float*)d_in[10];
    const float* Ws = (const float*)d_in[11]; const float* bs = (const float*)d_in[12];
    const float* Wbeta = (const float*)d_in[13];
    const float* g1 = (const float*)d_in[14]; const float* b1 = (const float*)d_in[15];
    const float* Wf1 = (const float*)d_in[16]; const float* bf1 = (const float*)d_in[17];
    const float* Wf2 = (const float*)d_in[18]; const float* bf2 = (const float*)d_in[19];
    const float* g2 = (const float*)d_in[20]; const float* b2 = (const float*)d_in[21];

    char* ws = (char*)d_ws;
    size_t off = 0;
    #define ALLOC(ptr, type, bytes) type* ptr = (type*)(ws + off); off = (off + (size_t)(bytes) + 255) & ~(size_t)255;
    ALLOC(wqkvsT, unsigned short, 640 * 128 * 2)
    ALLOC(wf1T,   unsigned short, 512 * 128 * 2)
    ALLOC(wf2T,   unsigned short, 128 * 512 * 2)
    ALLOC(biasq,  float,          640 * 4)
    ALLOC(qb,     float,          (size_t)NN * 128 * 4)     // 25.6 MB
    ALLOC(kvb,    unsigned short, (size_t)NN * 256 * 2)     // 25.6 MB (ff1 overlays qb+kvb)
    ALLOC(xrb,    float,          (size_t)NN * 128 * 4)     // 25.6 MB
    ALLOC(h,      float,          (size_t)NN * 128 * 4)     // 25.6 MB
    ALLOC(hbf,    unsigned int,   (size_t)NN * 128 * 2)     // 12.8 MB
    ALLOC(qweb,   float,          (size_t)NN * 64 * 4)      // 12.8 MB
    ALLOC(qbeb,   float,          (size_t)NN * 4 * 4)       // 0.8 MB
    ALLOC(deg,    int,            2 * NN * 4)               // deg + cursor, one region
    ALLOC(row_start, int,         (NN + 1) * 4)
    ALLOC(bsum,   int,            1024)
    ALLOC(srcs_sorted, int,       (size_t)EE * 4)           // 3.2 MB
    ALLOC(eas,    unsigned short, (size_t)EE * 16 * 2)      // 25.6 MB
    #undef ALLOC
    int* cursor = deg + NN;
    unsigned short* ff1 = (unsigned short*)qb;   // qb+kvb contiguous overlay

    hipMemsetAsync(deg, 0, (size_t)2 * NN * 4, stream);

    pack_w<<<835, 256, 0, stream>>>(Wq, Wk, Wv, Ws, bq, bk, bv, bs, Wf1, Wf2, We, be,
                                    wqkvsT, wf1T, wf2T, biasq);

    // q|kv|xr|qwe|qbe projections (Nn=640, 128x128 tiles)
    gemm_k<false, 2><<<391 * 5, 256, 0, stream>>>(x, wqkvsT, biasq, nullptr,
                                                  qb, kvb, xrb, qweb, qbeb,
                                                  nullptr, nullptr, nullptr, NN, 640, 128);

    // CSR by dst + permuted src/eattr
    hist_k<<<3125, 256, 0, stream>>>(eindex + EE, deg);
    scan_phaseA<<<196, 256, 0, stream>>>(deg, row_start, bsum);
    scan_phaseB<<<1, 256, 0, stream>>>(bsum, 196);
    scan_phaseC<<<196, 256, 0, stream>>>(row_start, bsum);
    scatter_k<<<3125, 256, 0, stream>>>(eindex, eindex + EE, eattr, row_start,
                                        cursor, srcs_sorted, eas);

    // fused attention + beta gate + residual + LN1
    attn_kernel<<<12500, 256, 0, stream>>>(qb, (const unsigned int*)kvb, xrb, x,
                                           eas, srcs_sorted, row_start, qweb, qbeb,
                                           We, be, Wbeta, g1, b1, h, hbf);

    // FFN1 (ff1 overlays qb/kvb — dead after attn)
    gemm_k<true, 1><<<391 * 4, 256, 0, stream>>>(hbf, wf1T, bf1, ff1,
                                                 nullptr, nullptr, nullptr, nullptr, nullptr,
                                                 nullptr, nullptr, nullptr, NN, 512, 128);
    // FFN2 + residual + LN2 fused -> d_out
    gemm_k<true, 3><<<391, 256, 0, stream>>>(ff1, wf2T, bf2, d_out,
                                             nullptr, nullptr, nullptr, nullptr, nullptr,
                                             h, g2, b2, NN, 128, 512);
}